// Round 1
// baseline (23.348 us; speedup 1.0000x reference)
//
#include <hip/hip_runtime.h>

#define MARGIN1 0.5f
#define MARGIN2 1.0f

// One wave (64 lanes) per group of 3 consecutive rows (labels 0,1,2 within
// each group by construction; mapped via label reads + branchless selects).
// D = 512 floats per row: lane l covers floats [4l,4l+4) and [256+4l, 256+4l+4)
// of each row -> 6 coalesced float4 loads per lane per group.
__global__ __launch_bounds__(256) void soso_main_kernel(
    const int* __restrict__ lab,
    const float* __restrict__ emb,
    const float* __restrict__ proto,
    float* __restrict__ partial,
    int ngroups)
{
    const int lane = threadIdx.x & 63;
    const int wid  = threadIdx.x >> 6;            // 0..3
    const int wavesPerGrid = gridDim.x * 4;
    const int gwave = blockIdx.x * 4 + wid;

    // Hoist proto fragment into registers (reused across all groups).
    const float4 p0 = *reinterpret_cast<const float4*>(proto + 4 * lane);
    const float4 p1 = *reinterpret_cast<const float4*>(proto + 256 + 4 * lane);

    float acc = 0.0f;

    for (int g = gwave; g < ngroups; g += wavesPerGrid) {
        const float* base = emb + (size_t)g * 3u * 512u;
        float dsum[3];
#pragma unroll
        for (int r = 0; r < 3; ++r) {
            const float* row = base + r * 512;
            const float4 e0 = *reinterpret_cast<const float4*>(row + 4 * lane);
            const float4 e1 = *reinterpret_cast<const float4*>(row + 256 + 4 * lane);
            float s = 0.0f, t;
            t = p0.x - e0.x; s = fmaf(t, t, s);
            t = p0.y - e0.y; s = fmaf(t, t, s);
            t = p0.z - e0.z; s = fmaf(t, t, s);
            t = p0.w - e0.w; s = fmaf(t, t, s);
            t = p1.x - e1.x; s = fmaf(t, t, s);
            t = p1.y - e1.y; s = fmaf(t, t, s);
            t = p1.z - e1.z; s = fmaf(t, t, s);
            t = p1.w - e1.w; s = fmaf(t, t, s);
            // 64-lane butterfly reduce; all lanes end with full row sum
#pragma unroll
            for (int off = 32; off > 0; off >>= 1)
                s += __shfl_xor(s, off, 64);
            dsum[r] = s;
        }
        // Wave-uniform label reads for this group (broadcast from cache).
        const int l0 = lab[3 * g + 0];
        const int l1 = lab[3 * g + 1];
        const int l2 = lab[3 * g + 2];
        // Branchless map: d_c = dsum of the row whose label == c.
        const float d1 = (l0 == 0) ? dsum[0] : (l1 == 0) ? dsum[1] : dsum[2];
        const float d2 = (l0 == 1) ? dsum[0] : (l1 == 1) ? dsum[1] : dsum[2];
        const float d3 = (l0 == 2) ? dsum[0] : (l1 == 2) ? dsum[1] : dsum[2];

        acc += fmaxf(d1 - d2 + MARGIN1, 0.0f)
             + fmaxf(d2 - d3 + MARGIN1, 0.0f)
             + fmaxf(d1 - d3 + MARGIN2, 0.0f);
    }

    // acc is wave-uniform; reduce the 4 waves of this block via LDS.
    __shared__ float smem[4];
    if (lane == 0) smem[wid] = acc;
    __syncthreads();
    if (threadIdx.x == 0)
        partial[blockIdx.x] = smem[0] + smem[1] + smem[2] + smem[3];
}

// Deterministic single-block reduction of per-block partials.
__global__ __launch_bounds__(256) void soso_reduce_kernel(
    const float* __restrict__ partial,
    float* __restrict__ out,
    int n,
    float inv_count)
{
    float s = 0.0f;
    for (int i = threadIdx.x; i < n; i += 256)
        s += partial[i];
#pragma unroll
    for (int off = 32; off > 0; off >>= 1)
        s += __shfl_xor(s, off, 64);
    __shared__ float smem[4];
    if ((threadIdx.x & 63) == 0) smem[threadIdx.x >> 6] = s;
    __syncthreads();
    if (threadIdx.x == 0)
        out[0] = (smem[0] + smem[1] + smem[2] + smem[3]) * inv_count;
}

extern "C" void kernel_launch(void* const* d_in, const int* in_sizes, int n_in,
                              void* d_out, int out_size, void* d_ws, size_t ws_size,
                              hipStream_t stream)
{
    const int*   lab   = (const int*)d_in[0];    // true_label [B] int32
    const float* emb   = (const float*)d_in[1];  // embedding  [B,512] f32
    const float* proto = (const float*)d_in[2];  // proto      [512]   f32
    float* out = (float*)d_out;

    const int B = in_sizes[0];
    const int ngroups = B / 3;                   // 16384

    float* partial = (float*)d_ws;               // 2048 floats of scratch
    const int blocks = 2048;                     // 256 CUs x 8 blocks, grid-stride

    soso_main_kernel<<<blocks, 256, 0, stream>>>(lab, emb, proto, partial, ngroups);
    soso_reduce_kernel<<<1, 256, 0, stream>>>(partial, out, blocks,
                                              1.0f / (float)ngroups);
}